// Round 3
// baseline (429.182 us; speedup 1.0000x reference)
//
#include <hip/hip_runtime.h>
#include <hip/hip_bf16.h>

typedef __attribute__((ext_vector_type(8))) short bf16x8_t;
typedef __attribute__((ext_vector_type(4))) float f32x4_t;
typedef __attribute__((ext_vector_type(8))) unsigned short u16x8_t;

__device__ inline unsigned short f2bf(float x) {
    union { float f; unsigned int u; } v; v.f = x;
    unsigned int r = v.u + 0x7FFFu + ((v.u >> 16) & 1u);
    return (unsigned short)(r >> 16);
}

__device__ inline void gl_lds16(const void* g, void* l) {
    __builtin_amdgcn_global_load_lds(
        (const __attribute__((address_space(1))) void*)g,
        (__attribute__((address_space(3))) void*)l, 16, 0, 0);
}

// ---------------- f32 -> bf16 convert (8 elems/thread/iter) ----------------
__global__ __launch_bounds__(256) void f32_to_bf16(
    const float* __restrict__ src, unsigned short* __restrict__ dst, int n8) {
    int stride = gridDim.x * blockDim.x;
    for (int i = blockIdx.x * blockDim.x + threadIdx.x; i < n8; i += stride) {
        const float4* p = (const float4*)(src + (size_t)i * 8);
        float4 a = p[0], b = p[1];
        u16x8_t v;
        v[0] = f2bf(a.x); v[1] = f2bf(a.y); v[2] = f2bf(a.z); v[3] = f2bf(a.w);
        v[4] = f2bf(b.x); v[5] = f2bf(b.y); v[6] = f2bf(b.z); v[7] = f2bf(b.w);
        *(u16x8_t*)(dst + (size_t)i * 8) = v;
    }
}

// ---------------- 256x256 tile, 8-wave, counted-vmcnt pipelined GEMM+LSE ---
// MODE 0: overlap. M=2304 (9 tiles), batch=v (0..7).   grid 648 = 8*81
// MODE 1: tile.    M=576 (3 tiles, padded), batch 0..63. grid 576 = 8*72
template <int MODE>
__global__ __launch_bounds__(512, 2) void gemm256_lse(
    const unsigned short* __restrict__ z1b, const unsigned short* __restrict__ z2b,
    float* __restrict__ rowsum, float* __restrict__ colsum,
    float* __restrict__ diag) {
    constexpr int M  = (MODE == 0) ? 2304 : 576;
    constexpr int TM = (MODE == 0) ? 9 : 3;
    constexpr int NB = (MODE == 0) ? (9 * 9 * 8) : (3 * 3 * 64);
    constexpr float inv_tau = (MODE == 0) ? (1.0f / 0.07f) : (1.0f / 0.2f);

    const int tid  = threadIdx.x;
    const int lane = tid & 63;
    const int w    = tid >> 6;        // 0..7
    const int wM   = w >> 2;          // 0..1  (rows: wM*128)
    const int wN   = w & 3;           // 0..3  (cols: wN*64)
    const int lr   = lane & 15;
    const int lg   = lane >> 4;

    // T1: XCD-aware block swizzle (NB divisible by 8 in both modes)
    const int bid   = blockIdx.x;
    const int lb    = (bid & 7) * (NB >> 3) + (bid >> 3);
    const int batch = lb / (TM * TM);
    const int rem   = lb - batch * (TM * TM);
    const int brow  = rem / TM;
    const int bcol  = rem - brow * TM;

    // LDS: buf c: A at c*32768, B at c*32768+16384 (ushort units). 128 KiB.
    __shared__ unsigned short smem[65536];
    __shared__ int offA[256], offB[256];

    if (tid < 256) {
        int r = brow * 256 + tid;
        int off;
        if (MODE == 0) {
            int b = r / 288, rm = r % 288, h = rm / 12, j = rm % 12;
            off = ((b * 8 + batch) * 576 + h * 24 + 12 + j) * 768;
        } else {
            off = ((r < M) ? (batch * 576 + r) : (batch * 576)) * 768;
        }
        offA[tid] = off;
    } else {
        int c = bcol * 256 + (tid - 256);
        int off;
        if (MODE == 0) {
            int b = c / 288, rm = c % 288, h = rm / 12, j = rm % 12;
            off = ((b * 8 + ((batch + 1) & 7)) * 576 + h * 24 + j) * 768;
        } else {
            off = ((c < M) ? (batch * 576 + c) : (batch * 576)) * 768;
        }
        offB[tid - 256] = off;
    }
    __syncthreads();

    // staging constants: thread stages row ra*64+(tid>>3), phys slot tid&7.
    // T2 swizzle: linear LDS dest; global source fetches logical slot (phys ^ (row&7)).
    const int srow = tid >> 3;
    const int slot = tid & 7;
    const int sswz = (slot ^ (srow & 7)) << 3;   // element offset within row
    int srcA[4], srcB[4];
#pragma unroll
    for (int ra = 0; ra < 4; ++ra) {
        srcA[ra] = offA[ra * 64 + srow] + sswz;
        srcB[ra] = offB[ra * 64 + srow] + sswz;
    }
    const int dstw = w * 512;   // wave-uniform LDS chunk (ushort units), +ra*4096

    // read constants (ushort units within a 16 K-ushort tile)
    const int arow  = (wM * 128 + lr) * 64;
    const int brow_ = (wN * 64 + lr) * 64;
    int slt[2];
#pragma unroll
    for (int h = 0; h < 2; ++h) slt[h] = (((h << 2) | lg) ^ (lr & 7)) << 3;

    f32x4_t acc[8][4];
#pragma unroll
    for (int i = 0; i < 8; ++i)
#pragma unroll
        for (int j = 0; j < 4; ++j) acc[i][j] = (f32x4_t){0.f, 0.f, 0.f, 0.f};

#define STAGE(KT, C) do { \
    const int k0_ = (KT) * 64; \
    _Pragma("unroll") \
    for (int ra = 0; ra < 4; ++ra) { \
        gl_lds16(z1b + srcA[ra] + k0_, &smem[(C) * 32768 + ra * 4096 + dstw]); \
        gl_lds16(z2b + srcB[ra] + k0_, &smem[(C) * 32768 + 16384 + ra * 4096 + dstw]); \
    } } while (0)

    STAGE(0, 0);
    asm volatile("s_waitcnt vmcnt(0)" ::: "memory");
    __builtin_amdgcn_s_barrier();

#pragma unroll 2
    for (int kt = 0; kt < 12; ++kt) {
        const int c = kt & 1;
        if (kt < 11) STAGE(kt + 1, c ^ 1);   // loads fly under compute (T4)
        const unsigned short* A = &smem[c * 32768];
        const unsigned short* B = &smem[c * 32768 + 16384];
#pragma unroll
        for (int h = 0; h < 2; ++h) {
            bf16x8_t af[8], bf[4];
#pragma unroll
            for (int i = 0; i < 8; ++i)
                af[i] = *(const bf16x8_t*)&A[arow + i * 1024 + slt[h]];
#pragma unroll
            for (int j = 0; j < 4; ++j)
                bf[j] = *(const bf16x8_t*)&B[brow_ + j * 1024 + slt[h]];
            __builtin_amdgcn_s_setprio(1);
#pragma unroll
            for (int i = 0; i < 8; ++i)
#pragma unroll
                for (int j = 0; j < 4; ++j)
                    acc[i][j] = __builtin_amdgcn_mfma_f32_16x16x32_bf16(
                        af[i], bf[j], acc[i][j], 0, 0, 0);
            __builtin_amdgcn_s_setprio(0);
        }
        asm volatile("s_waitcnt vmcnt(0)" ::: "memory");
        __builtin_amdgcn_s_barrier();
    }
#undef STAGE

    // Epilogue: L = acc*inv_tau; exp row/col partial sums; diag.
    const int rowbase = brow * 256 + wM * 128;
    const int colbase = bcol * 256 + wN * 64;
    float colacc[4] = {0.f, 0.f, 0.f, 0.f};
#pragma unroll
    for (int i = 0; i < 8; ++i) {
#pragma unroll
        for (int reg = 0; reg < 4; ++reg) {
            int row = rowbase + i * 16 + lg * 4 + reg;
            bool rv = row < M;
            float rp = 0.f;
#pragma unroll
            for (int j = 0; j < 4; ++j) {
                int col = colbase + j * 16 + lr;
                float L = acc[i][j][reg] * inv_tau;
                float e = (rv && (col < M)) ? __expf(L) : 0.f;
                rp += e;
                colacc[j] += e;
                if (rv && row == col) diag[batch * M + row] = L;
            }
#pragma unroll
            for (int s = 1; s < 16; s <<= 1) rp += __shfl_xor(rp, s);
            if (lr == 0 && rv) atomicAdd(&rowsum[batch * M + row], rp);
        }
    }
#pragma unroll
    for (int j = 0; j < 4; ++j) {
        float cv = colacc[j];
        cv += __shfl_xor(cv, 16);
        cv += __shfl_xor(cv, 32);
        int col = colbase + j * 16 + lr;
        if (lg == 0 && col < M) atomicAdd(&colsum[batch * M + col], cv);
    }
}

// ---------------- fallback path (R1, convert-in-flight, verified) ----------
template <int MODE>
__global__ __launch_bounds__(256) void fused_gemm_lse(
    const float* __restrict__ z1, const float* __restrict__ z2,
    float* __restrict__ rowsum, float* __restrict__ colsum,
    float* __restrict__ diag) {
    constexpr int M = (MODE == 0) ? 2304 : 576;
    constexpr float inv_tau = (MODE == 0) ? (1.0f / 0.07f) : (1.0f / 0.2f);

    const int tid  = threadIdx.x;
    const int lane = tid & 63;
    const int w    = tid >> 6;
    const int wM   = w >> 1;
    const int wN   = w & 1;
    const int lr   = lane & 15;
    const int lg   = lane >> 4;
    const int brow = blockIdx.y, bcol = blockIdx.x, batch = blockIdx.z;

    __shared__ unsigned short lA[128][72];
    __shared__ unsigned short lB[128][72];
    __shared__ int offA[128];
    __shared__ int offB[128];

    if (tid < 128) {
        int r = brow * 128 + tid;
        int off;
        if (MODE == 0) {
            int b = r / 288, rem = r % 288;
            int h = rem / 12, j = rem % 12;
            off = ((b * 8 + batch) * 576 + h * 24 + 12 + j) * 768;
        } else {
            off = (r < M) ? (batch * 576 + r) * 768 : -1;
        }
        offA[tid] = off;
    } else {
        int c = bcol * 128 + (tid - 128);
        int off;
        if (MODE == 0) {
            int b = c / 288, rem = c % 288;
            int h = rem / 12, j = rem % 12;
            off = ((b * 8 + ((batch + 1) & 7)) * 576 + h * 24 + j) * 768;
        } else {
            off = (c < M) ? (batch * 576 + c) * 768 : -1;
        }
        offB[tid - 128] = off;
    }
    __syncthreads();

    f32x4_t acc[4][4];
#pragma unroll
    for (int i = 0; i < 4; ++i)
#pragma unroll
        for (int j = 0; j < 4; ++j) acc[i][j] = (f32x4_t){0.f, 0.f, 0.f, 0.f};

    for (int kt = 0; kt < 12; ++kt) {
        const int k0 = kt * 64;
#pragma unroll
        for (int rr = 0; rr < 8; ++rr) {
            int f   = tid + (rr << 8);
            int row = f >> 4;
            int c4  = f & 15;
            int oA = offA[row], oB = offB[row];
            float4 va = make_float4(0.f, 0.f, 0.f, 0.f);
            float4 vb = make_float4(0.f, 0.f, 0.f, 0.f);
            if (oA >= 0) va = *(const float4*)(z1 + oA + k0 + (c4 << 2));
            if (oB >= 0) vb = *(const float4*)(z2 + oB + k0 + (c4 << 2));
            ushort4 sa, sb;
            sa.x = f2bf(va.x); sa.y = f2bf(va.y); sa.z = f2bf(va.z); sa.w = f2bf(va.w);
            sb.x = f2bf(vb.x); sb.y = f2bf(vb.y); sb.z = f2bf(vb.z); sb.w = f2bf(vb.w);
            *(ushort4*)&lA[row][c4 << 2] = sa;
            *(ushort4*)&lB[row][c4 << 2] = sb;
        }
        __syncthreads();
#pragma unroll
        for (int kk = 0; kk < 64; kk += 32) {
            bf16x8_t av[4], bv[4];
#pragma unroll
            for (int i = 0; i < 4; ++i) {
                av[i] = *(const bf16x8_t*)&lA[wM * 64 + i * 16 + lr][kk + lg * 8];
                bv[i] = *(const bf16x8_t*)&lB[wN * 64 + i * 16 + lr][kk + lg * 8];
            }
#pragma unroll
            for (int i = 0; i < 4; ++i)
#pragma unroll
                for (int j = 0; j < 4; ++j)
                    acc[i][j] = __builtin_amdgcn_mfma_f32_16x16x32_bf16(
                        av[i], bv[j], acc[i][j], 0, 0, 0);
        }
        __syncthreads();
    }

    const int rowbase = brow * 128 + wM * 64;
    const int colbase = bcol * 128 + wN * 64;
    float colacc[4] = {0.f, 0.f, 0.f, 0.f};
#pragma unroll
    for (int i = 0; i < 4; ++i) {
#pragma unroll
        for (int reg = 0; reg < 4; ++reg) {
            int row = rowbase + i * 16 + lg * 4 + reg;
            bool rv = row < M;
            float rp = 0.f;
#pragma unroll
            for (int j = 0; j < 4; ++j) {
                int col = colbase + j * 16 + lr;
                float L = acc[i][j][reg] * inv_tau;
                float e = (rv && (col < M)) ? __expf(L) : 0.f;
                rp += e;
                colacc[j] += e;
                if (rv && row == col) diag[batch * M + row] = L;
            }
#pragma unroll
            for (int s = 1; s < 16; s <<= 1) rp += __shfl_xor(rp, s);
            if (lr == 0 && rv) atomicAdd(&rowsum[batch * M + row], rp);
        }
    }
#pragma unroll
    for (int j = 0; j < 4; ++j) {
        float c = colacc[j];
        c += __shfl_xor(c, 16);
        c += __shfl_xor(c, 32);
        int col = colbase + j * 16 + lr;
        if (lg == 0 && col < M) atomicAdd(&colsum[batch * M + col], c);
    }
}

// ws float layout:
// [0) rs_ov 18432 | [18432) cs_ov 18432 | [36864) dg_ov 18432
// [55296) rs_t 36864 | [92160) cs_t 36864 | [129024) dg_t 36864 -> 165888
// fast path: bf16 z1 copy at byte 663552, z2 after.
__global__ void finalize_kernel(const float* __restrict__ ws, float* __restrict__ out) {
    const float* rs_ov = ws;
    const float* cs_ov = ws + 18432;
    const float* dg_ov = ws + 36864;
    const float* rs_t  = ws + 55296;
    const float* cs_t  = ws + 92160;
    const float* dg_t  = ws + 129024;
    float s_ov = 0.f, s_t = 0.f;
    for (int i = threadIdx.x; i < 18432; i += 256)
        s_ov += logf(rs_ov[i]) + logf(cs_ov[i]) - 2.f * dg_ov[i];
    for (int i = threadIdx.x; i < 36864; i += 256)
        s_t += logf(rs_t[i]) + logf(cs_t[i]) - 2.f * dg_t[i];
#pragma unroll
    for (int s = 1; s < 64; s <<= 1) {
        s_ov += __shfl_xor(s_ov, s);
        s_t  += __shfl_xor(s_t, s);
    }
    __shared__ float red[2][4];
    int w = threadIdx.x >> 6;
    if ((threadIdx.x & 63) == 0) { red[0][w] = s_ov; red[1][w] = s_t; }
    __syncthreads();
    if (threadIdx.x == 0) {
        float a = red[0][0] + red[0][1] + red[0][2] + red[0][3];
        float b = red[1][0] + red[1][1] + red[1][2] + red[1][3];
        out[0] = 0.5f * a / 18432.f + 0.05f * b / 36864.f;
    }
}

extern "C" void kernel_launch(void* const* d_in, const int* in_sizes, int n_in,
                              void* d_out, int out_size, void* d_ws, size_t ws_size,
                              hipStream_t stream) {
    const float* z1 = (const float*)d_in[0];
    const float* z2 = (const float*)d_in[1];
    float* out = (float*)d_out;
    float* ws  = (float*)d_ws;

    const size_t N_ELEM = (size_t)64 * 576 * 768;
    const size_t ACC_B  = 165888 * sizeof(float);
    const size_t BF_B   = N_ELEM * 2;
    const size_t NEED   = ACC_B + 2 * BF_B;

    hipMemsetAsync(d_ws, 0, ACC_B, stream);
    dim3 blk256(256, 1, 1);

    if (ws_size >= NEED) {
        unsigned short* z1b = (unsigned short*)((char*)d_ws + ACC_B);
        unsigned short* z2b = z1b + N_ELEM;
        int n8 = (int)(N_ELEM / 8);
        f32_to_bf16<<<2048, blk256, 0, stream>>>(z1, z1b, n8);
        f32_to_bf16<<<2048, blk256, 0, stream>>>(z2, z2b, n8);
        gemm256_lse<0><<<648, 512, 0, stream>>>(
            z1b, z2b, ws, ws + 18432, ws + 36864);
        gemm256_lse<1><<<576, 512, 0, stream>>>(
            z1b, z2b, ws + 55296, ws + 92160, ws + 129024);
    } else {
        fused_gemm_lse<0><<<dim3(18, 18, 8), blk256, 0, stream>>>(
            z1, z2, ws, ws + 18432, ws + 36864);
        fused_gemm_lse<1><<<dim3(5, 5, 64), blk256, 0, stream>>>(
            z1, z2, ws + 55296, ws + 92160, ws + 129024);
    }
    finalize_kernel<<<1, 256, 0, stream>>>(ws, out);
}

// Round 4
// 360.630 us; speedup vs baseline: 1.1901x; 1.1901x over previous
//
#include <hip/hip_runtime.h>
#include <hip/hip_bf16.h>

typedef __attribute__((ext_vector_type(8))) short bf16x8_t;
typedef __attribute__((ext_vector_type(4))) float f32x4_t;
typedef __attribute__((ext_vector_type(8))) unsigned short u16x8_t;

__device__ inline unsigned short f2bf(float x) {
    union { float f; unsigned int u; } v; v.f = x;
    unsigned int r = v.u + 0x7FFFu + ((v.u >> 16) & 1u);
    return (unsigned short)(r >> 16);
}

__device__ inline void gl_lds16(const void* g, void* l) {
    __builtin_amdgcn_global_load_lds(
        (const __attribute__((address_space(1))) void*)g,
        (__attribute__((address_space(3))) void*)l, 16, 0, 0);
}

// ---------------- f32 -> bf16 convert (8 elems/thread/iter) ----------------
__global__ __launch_bounds__(256) void f32_to_bf16(
    const float* __restrict__ src, unsigned short* __restrict__ dst, int n8) {
    int stride = gridDim.x * blockDim.x;
    for (int i = blockIdx.x * blockDim.x + threadIdx.x; i < n8; i += stride) {
        const float4* p = (const float4*)(src + (size_t)i * 8);
        float4 a = p[0], b = p[1];
        u16x8_t v;
        v[0] = f2bf(a.x); v[1] = f2bf(a.y); v[2] = f2bf(a.z); v[3] = f2bf(a.w);
        v[4] = f2bf(b.x); v[5] = f2bf(b.y); v[6] = f2bf(b.z); v[7] = f2bf(b.w);
        *(u16x8_t*)(dst + (size_t)i * 8) = v;
    }
}

// ------- 256x256 tile, BK=32, 4-slot LDS ring, counted-vmcnt pipeline ------
// MODE 0: overlap. M=2304 (9x9 tiles), batch=v (0..7).  grid 648 = 8*81
// MODE 1: tile.    M=576 (3x3, padded), batch 0..63.    grid 576 = 8*72
// LDS slot s (32KB): A[256][32] bf16 at s*16384, B[256][32] at s*16384+8192
// (ushort units). 24 K-tiles; stage t+3 during t; vmcnt(8) per tile (ring
// depth 3 in flight = 12 ops, wait oldest 4). Tail: vmcnt(8)/(4)/(0).
template <int MODE>
__global__ __launch_bounds__(512, 2) void gemm256_lse(
    const unsigned short* __restrict__ z1b, const unsigned short* __restrict__ z2b,
    float* __restrict__ rowsum, float* __restrict__ colsum,
    float* __restrict__ diag) {
    constexpr int M  = (MODE == 0) ? 2304 : 576;
    constexpr int TM = (MODE == 0) ? 9 : 3;
    constexpr int NB = (MODE == 0) ? (9 * 9 * 8) : (3 * 3 * 64);
    constexpr float inv_tau = (MODE == 0) ? (1.0f / 0.07f) : (1.0f / 0.2f);

    const int tid  = threadIdx.x;
    const int lane = tid & 63;
    const int w    = tid >> 6;        // 0..7
    const int wM   = w >> 2;          // 0..1  (rows: wM*128)
    const int wN   = w & 3;           // 0..3  (cols: wN*64)
    const int lr   = lane & 15;
    const int lg   = lane >> 4;       // 0..3 (K-slot of 8 elems within 32)

    // T1: XCD-aware bijective block swizzle (NB % 8 == 0 in both modes)
    const int bid   = blockIdx.x;
    const int lb    = (bid & 7) * (NB >> 3) + (bid >> 3);
    const int batch = lb / (TM * TM);
    const int rem   = lb - batch * (TM * TM);
    const int brow  = rem / TM;
    const int bcol  = rem - brow * TM;

    __shared__ unsigned short smem[65536];   // 4 slots x 16384 ushorts = 128 KiB
    __shared__ int offA[256], offB[256];

    if (tid < 256) {
        int r = brow * 256 + tid;
        int off;
        if (MODE == 0) {
            int b = r / 288, rm = r % 288, h = rm / 12, j = rm % 12;
            off = ((b * 8 + batch) * 576 + h * 24 + 12 + j) * 768;
        } else {
            off = ((r < M) ? (batch * 576 + r) : (batch * 576)) * 768;
        }
        offA[tid] = off;
    } else {
        int c = bcol * 256 + (tid - 256);
        int off;
        if (MODE == 0) {
            int b = c / 288, rm = c % 288, h = rm / 12, j = rm % 12;
            off = ((b * 8 + ((batch + 1) & 7)) * 576 + h * 24 + j) * 768;
        } else {
            off = ((c < M) ? (batch * 576 + c) : (batch * 576)) * 768;
        }
        offB[tid - 256] = off;
    }
    __syncthreads();

    // staging: position p = row*4 + slot16B; thread covers p = tid and tid+512
    const int r0 = tid >> 2;
    const int c0 = (tid & 3) * 8;            // element offset within 32-elem row
    const int sA0 = offA[r0] + c0;
    const int sA1 = offA[128 + r0] + c0;
    const int sB0 = offB[r0] + c0;
    const int sB1 = offB[128 + r0] + c0;
    const int dW  = w * 512;                 // wave-uniform LDS chunk (ushorts)

    // read offsets (ushort units within a slot)
    int aoff[8], boff[4];
#pragma unroll
    for (int i = 0; i < 8; ++i) aoff[i] = (wM * 128 + i * 16 + lr) * 32 + lg * 8;
#pragma unroll
    for (int j = 0; j < 4; ++j) boff[j] = 8192 + (wN * 64 + j * 16 + lr) * 32 + lg * 8;

    f32x4_t acc[8][4];
#pragma unroll
    for (int i = 0; i < 8; ++i)
#pragma unroll
        for (int j = 0; j < 4; ++j) acc[i][j] = (f32x4_t){0.f, 0.f, 0.f, 0.f};

#define STAGE(T) do { \
    const int sb_ = ((T) & 3) * 16384; \
    const int k0_ = (T) * 32; \
    gl_lds16(z1b + sA0 + k0_, &smem[sb_ + dW]); \
    gl_lds16(z1b + sA1 + k0_, &smem[sb_ + 4096 + dW]); \
    gl_lds16(z2b + sB0 + k0_, &smem[sb_ + 8192 + dW]); \
    gl_lds16(z2b + sB1 + k0_, &smem[sb_ + 12288 + dW]); \
} while (0)

#define COMPUTE(T) do { \
    const unsigned short* S_ = &smem[((T) & 3) * 16384]; \
    bf16x8_t af[8], bf[4]; \
    _Pragma("unroll") \
    for (int i = 0; i < 8; ++i) af[i] = *(const bf16x8_t*)&S_[aoff[i]]; \
    _Pragma("unroll") \
    for (int j = 0; j < 4; ++j) bf[j] = *(const bf16x8_t*)&S_[boff[j]]; \
    __builtin_amdgcn_s_setprio(1); \
    _Pragma("unroll") \
    for (int i = 0; i < 8; ++i) \
        _Pragma("unroll") \
        for (int j = 0; j < 4; ++j) \
            acc[i][j] = __builtin_amdgcn_mfma_f32_16x16x32_bf16( \
                af[i], bf[j], acc[i][j], 0, 0, 0); \
    __builtin_amdgcn_s_setprio(0); \
} while (0)

    STAGE(0); STAGE(1); STAGE(2);            // 12 outstanding

    for (int t = 0; t < 21; ++t) {
        asm volatile("s_waitcnt vmcnt(8)" ::: "memory");   // tile t landed
        __builtin_amdgcn_s_barrier();
        __builtin_amdgcn_sched_barrier(0);
        STAGE(t + 3);                        // overwrites slot (t-1)&3: safe
        COMPUTE(t);
    }
    asm volatile("s_waitcnt vmcnt(8)" ::: "memory");
    __builtin_amdgcn_s_barrier();
    __builtin_amdgcn_sched_barrier(0);
    COMPUTE(21);
    asm volatile("s_waitcnt vmcnt(4)" ::: "memory");
    __builtin_amdgcn_s_barrier();
    __builtin_amdgcn_sched_barrier(0);
    COMPUTE(22);
    asm volatile("s_waitcnt vmcnt(0)" ::: "memory");
    __builtin_amdgcn_s_barrier();
    __builtin_amdgcn_sched_barrier(0);
    COMPUTE(23);
#undef STAGE
#undef COMPUTE

    // Epilogue: L = acc*inv_tau; exp row/col partial sums; diag.
    const int rowbase = brow * 256 + wM * 128;
    const int colbase = bcol * 256 + wN * 64;
    float colacc[4] = {0.f, 0.f, 0.f, 0.f};
#pragma unroll
    for (int i = 0; i < 8; ++i) {
#pragma unroll
        for (int reg = 0; reg < 4; ++reg) {
            int row = rowbase + i * 16 + lg * 4 + reg;
            bool rv = row < M;
            float rp = 0.f;
#pragma unroll
            for (int j = 0; j < 4; ++j) {
                int col = colbase + j * 16 + lr;
                float L = acc[i][j][reg] * inv_tau;
                float e = (rv && (col < M)) ? __expf(L) : 0.f;
                rp += e;
                colacc[j] += e;
                if (rv && row == col) diag[batch * M + row] = L;
            }
#pragma unroll
            for (int s = 1; s < 16; s <<= 1) rp += __shfl_xor(rp, s);
            if (lr == 0 && rv) atomicAdd(&rowsum[batch * M + row], rp);
        }
    }
#pragma unroll
    for (int j = 0; j < 4; ++j) {
        float cv = colacc[j];
        cv += __shfl_xor(cv, 16);
        cv += __shfl_xor(cv, 32);
        int col = colbase + j * 16 + lr;
        if (lg == 0 && col < M) atomicAdd(&colsum[batch * M + col], cv);
    }
}

// ---------------- fallback path (R1, convert-in-flight, verified) ----------
template <int MODE>
__global__ __launch_bounds__(256) void fused_gemm_lse(
    const float* __restrict__ z1, const float* __restrict__ z2,
    float* __restrict__ rowsum, float* __restrict__ colsum,
    float* __restrict__ diag) {
    constexpr int M = (MODE == 0) ? 2304 : 576;
    constexpr float inv_tau = (MODE == 0) ? (1.0f / 0.07f) : (1.0f / 0.2f);

    const int tid  = threadIdx.x;
    const int lane = tid & 63;
    const int w    = tid >> 6;
    const int wM   = w >> 1;
    const int wN   = w & 1;
    const int lr   = lane & 15;
    const int lg   = lane >> 4;
    const int brow = blockIdx.y, bcol = blockIdx.x, batch = blockIdx.z;

    __shared__ unsigned short lA[128][72];
    __shared__ unsigned short lB[128][72];
    __shared__ int offA[128];
    __shared__ int offB[128];

    if (tid < 128) {
        int r = brow * 128 + tid;
        int off;
        if (MODE == 0) {
            int b = r / 288, rem = r % 288;
            int h = rem / 12, j = rem % 12;
            off = ((b * 8 + batch) * 576 + h * 24 + 12 + j) * 768;
        } else {
            off = (r < M) ? (batch * 576 + r) * 768 : -1;
        }
        offA[tid] = off;
    } else {
        int c = bcol * 128 + (tid - 128);
        int off;
        if (MODE == 0) {
            int b = c / 288, rem = c % 288;
            int h = rem / 12, j = rem % 12;
            off = ((b * 8 + ((batch + 1) & 7)) * 576 + h * 24 + j) * 768;
        } else {
            off = (c < M) ? (batch * 576 + c) * 768 : -1;
        }
        offB[tid - 128] = off;
    }
    __syncthreads();

    f32x4_t acc[4][4];
#pragma unroll
    for (int i = 0; i < 4; ++i)
#pragma unroll
        for (int j = 0; j < 4; ++j) acc[i][j] = (f32x4_t){0.f, 0.f, 0.f, 0.f};

    for (int kt = 0; kt < 12; ++kt) {
        const int k0 = kt * 64;
#pragma unroll
        for (int rr = 0; rr < 8; ++rr) {
            int f   = tid + (rr << 8);
            int row = f >> 4;
            int c4  = f & 15;
            int oA = offA[row], oB = offB[row];
            float4 va = make_float4(0.f, 0.f, 0.f, 0.f);
            float4 vb = make_float4(0.f, 0.f, 0.f, 0.f);
            if (oA >= 0) va = *(const float4*)(z1 + oA + k0 + (c4 << 2));
            if (oB >= 0) vb = *(const float4*)(z2 + oB + k0 + (c4 << 2));
            ushort4 sa, sb;
            sa.x = f2bf(va.x); sa.y = f2bf(va.y); sa.z = f2bf(va.z); sa.w = f2bf(va.w);
            sb.x = f2bf(vb.x); sb.y = f2bf(vb.y); sb.z = f2bf(vb.z); sb.w = f2bf(vb.w);
            *(ushort4*)&lA[row][c4 << 2] = sa;
            *(ushort4*)&lB[row][c4 << 2] = sb;
        }
        __syncthreads();
#pragma unroll
        for (int kk = 0; kk < 64; kk += 32) {
            bf16x8_t av[4], bv[4];
#pragma unroll
            for (int i = 0; i < 4; ++i) {
                av[i] = *(const bf16x8_t*)&lA[wM * 64 + i * 16 + lr][kk + lg * 8];
                bv[i] = *(const bf16x8_t*)&lB[wN * 64 + i * 16 + lr][kk + lg * 8];
            }
#pragma unroll
            for (int i = 0; i < 4; ++i)
#pragma unroll
                for (int j = 0; j < 4; ++j)
                    acc[i][j] = __builtin_amdgcn_mfma_f32_16x16x32_bf16(
                        av[i], bv[j], acc[i][j], 0, 0, 0);
        }
        __syncthreads();
    }

    const int rowbase = brow * 128 + wM * 64;
    const int colbase = bcol * 128 + wN * 64;
    float colacc[4] = {0.f, 0.f, 0.f, 0.f};
#pragma unroll
    for (int i = 0; i < 4; ++i) {
#pragma unroll
        for (int reg = 0; reg < 4; ++reg) {
            int row = rowbase + i * 16 + lg * 4 + reg;
            bool rv = row < M;
            float rp = 0.f;
#pragma unroll
            for (int j = 0; j < 4; ++j) {
                int col = colbase + j * 16 + lr;
                float L = acc[i][j][reg] * inv_tau;
                float e = (rv && (col < M)) ? __expf(L) : 0.f;
                rp += e;
                colacc[j] += e;
                if (rv && row == col) diag[batch * M + row] = L;
            }
#pragma unroll
            for (int s = 1; s < 16; s <<= 1) rp += __shfl_xor(rp, s);
            if (lr == 0 && rv) atomicAdd(&rowsum[batch * M + row], rp);
        }
    }
#pragma unroll
    for (int j = 0; j < 4; ++j) {
        float c = colacc[j];
        c += __shfl_xor(c, 16);
        c += __shfl_xor(c, 32);
        int col = colbase + j * 16 + lr;
        if (lg == 0 && col < M) atomicAdd(&colsum[batch * M + col], c);
    }
}

// ws float layout:
// [0) rs_ov 18432 | [18432) cs_ov 18432 | [36864) dg_ov 18432
// [55296) rs_t 36864 | [92160) cs_t 36864 | [129024) dg_t 36864 -> 165888
// fast path: bf16 z1 copy at byte 663552, z2 after.
__global__ void finalize_kernel(const float* __restrict__ ws, float* __restrict__ out) {
    const float* rs_ov = ws;
    const float* cs_ov = ws + 18432;
    const float* dg_ov = ws + 36864;
    const float* rs_t  = ws + 55296;
    const float* cs_t  = ws + 92160;
    const float* dg_t  = ws + 129024;
    float s_ov = 0.f, s_t = 0.f;
    for (int i = threadIdx.x; i < 18432; i += 256)
        s_ov += logf(rs_ov[i]) + logf(cs_ov[i]) - 2.f * dg_ov[i];
    for (int i = threadIdx.x; i < 36864; i += 256)
        s_t += logf(rs_t[i]) + logf(cs_t[i]) - 2.f * dg_t[i];
#pragma unroll
    for (int s = 1; s < 64; s <<= 1) {
        s_ov += __shfl_xor(s_ov, s);
        s_t  += __shfl_xor(s_t, s);
    }
    __shared__ float red[2][4];
    int w = threadIdx.x >> 6;
    if ((threadIdx.x & 63) == 0) { red[0][w] = s_ov; red[1][w] = s_t; }
    __syncthreads();
    if (threadIdx.x == 0) {
        float a = red[0][0] + red[0][1] + red[0][2] + red[0][3];
        float b = red[1][0] + red[1][1] + red[1][2] + red[1][3];
        out[0] = 0.5f * a / 18432.f + 0.05f * b / 36864.f;
    }
}

extern "C" void kernel_launch(void* const* d_in, const int* in_sizes, int n_in,
                              void* d_out, int out_size, void* d_ws, size_t ws_size,
                              hipStream_t stream) {
    const float* z1 = (const float*)d_in[0];
    const float* z2 = (const float*)d_in[1];
    float* out = (float*)d_out;
    float* ws  = (float*)d_ws;

    const size_t N_ELEM = (size_t)64 * 576 * 768;
    const size_t ACC_B  = 165888 * sizeof(float);
    const size_t BF_B   = N_ELEM * 2;
    const size_t NEED   = ACC_B + 2 * BF_B;

    hipMemsetAsync(d_ws, 0, ACC_B, stream);
    dim3 blk256(256, 1, 1);

    if (ws_size >= NEED) {
        unsigned short* z1b = (unsigned short*)((char*)d_ws + ACC_B);
        unsigned short* z2b = z1b + N_ELEM;
        int n8 = (int)(N_ELEM / 8);
        f32_to_bf16<<<2048, blk256, 0, stream>>>(z1, z1b, n8);
        f32_to_bf16<<<2048, blk256, 0, stream>>>(z2, z2b, n8);
        gemm256_lse<0><<<648, 512, 0, stream>>>(
            z1b, z2b, ws, ws + 18432, ws + 36864);
        gemm256_lse<1><<<576, 512, 0, stream>>>(
            z1b, z2b, ws + 55296, ws + 92160, ws + 129024);
    } else {
        fused_gemm_lse<0><<<dim3(18, 18, 8), blk256, 0, stream>>>(
            z1, z2, ws, ws + 18432, ws + 36864);
        fused_gemm_lse<1><<<dim3(5, 5, 64), blk256, 0, stream>>>(
            z1, z2, ws + 55296, ws + 92160, ws + 129024);
    }
    finalize_kernel<<<1, 256, 0, stream>>>(ws, out);
}

// Round 5
// 325.612 us; speedup vs baseline: 1.3181x; 1.1075x over previous
//
#include <hip/hip_runtime.h>
#include <hip/hip_bf16.h>

typedef __attribute__((ext_vector_type(8))) short bf16x8_t;
typedef __attribute__((ext_vector_type(4))) float f32x4_t;
typedef __attribute__((ext_vector_type(8))) unsigned short u16x8_t;

__device__ inline unsigned short f2bf(float x) {
    union { float f; unsigned int u; } v; v.f = x;
    unsigned int r = v.u + 0x7FFFu + ((v.u >> 16) & 1u);
    return (unsigned short)(r >> 16);
}

__device__ inline void gl_lds16(const void* g, void* l) {
    __builtin_amdgcn_global_load_lds(
        (const __attribute__((address_space(1))) void*)g,
        (__attribute__((address_space(3))) void*)l, 16, 0, 0);
}

// ---------------- f32 -> bf16 convert (8 elems/thread/iter) ----------------
__global__ __launch_bounds__(256) void f32_to_bf16(
    const float* __restrict__ src, unsigned short* __restrict__ dst, int n8) {
    int stride = gridDim.x * blockDim.x;
    for (int i = blockIdx.x * blockDim.x + threadIdx.x; i < n8; i += stride) {
        const float4* p = (const float4*)(src + (size_t)i * 8);
        float4 a = p[0], b = p[1];
        u16x8_t v;
        v[0] = f2bf(a.x); v[1] = f2bf(a.y); v[2] = f2bf(a.z); v[3] = f2bf(a.w);
        v[4] = f2bf(b.x); v[5] = f2bf(b.y); v[6] = f2bf(b.z); v[7] = f2bf(b.w);
        *(u16x8_t*)(dst + (size_t)i * 8) = v;
    }
}

// ------- 256x256 tile, BK=32, 4-slot ring, 2-phase/tile, swizzled LDS ------
// MODE 0: overlap. M=2304 (9x9 tiles), batch=v (0..7).  grid 648 = 8*81
// MODE 1: tile.    M=576 (3x3, padded), batch 0..63.    grid 576 = 8*72
// LDS slot s (32KB): A[256][32] at s*16384, B[256][32] at s*16384+8192 (ushorts).
// Swizzle: 16B-chunk phys = logical ^ ((row>>1)&3), applied on global source
// (inverse) and ds_read (forward); LDS dest linear (rule 21).
// Ring: stage tile t+3 during t; vmcnt(8) steady, tail 4/2/0 (never-drain T4).
template <int MODE>
__global__ __launch_bounds__(512, 2) void gemm256_lse(
    const unsigned short* __restrict__ z1b, const unsigned short* __restrict__ z2b,
    float* __restrict__ rowsum, float* __restrict__ colsum,
    float* __restrict__ diag) {
    constexpr int M  = (MODE == 0) ? 2304 : 576;
    constexpr int TM = (MODE == 0) ? 9 : 3;
    constexpr int NB = (MODE == 0) ? (9 * 9 * 8) : (3 * 3 * 64);
    constexpr float inv_tau = (MODE == 0) ? (1.0f / 0.07f) : (1.0f / 0.2f);

    const int tid  = threadIdx.x;
    const int lane = tid & 63;
    const int w    = tid >> 6;        // 0..7
    const int wM   = w >> 2;          // 0..1  (rows: wM*128)
    const int wN   = w & 3;           // 0..3  (cols: wN*64)
    const int lr   = lane & 15;
    const int lg   = lane >> 4;       // 0..3 (16B k-chunk within 32-elem row)

    // T1: XCD-aware bijective block swizzle (NB % 8 == 0 in both modes)
    const int bid   = blockIdx.x;
    const int lb    = (bid & 7) * (NB >> 3) + (bid >> 3);
    const int batch = lb / (TM * TM);
    const int rem   = lb - batch * (TM * TM);
    const int brow  = rem / TM;
    const int bcol  = rem - brow * TM;

    __shared__ unsigned short smem[65536];   // 4 slots x 16384 ushorts = 128 KiB
    __shared__ int offA[256], offB[256];

    if (tid < 256) {
        int r = brow * 256 + tid;
        int off;
        if (MODE == 0) {
            int b = r / 288, rm = r % 288, h = rm / 12, j = rm % 12;
            off = ((b * 8 + batch) * 576 + h * 24 + 12 + j) * 768;
        } else {
            off = ((r < M) ? (batch * 576 + r) : (batch * 576)) * 768;
        }
        offA[tid] = off;
    } else {
        int c = bcol * 256 + (tid - 256);
        int off;
        if (MODE == 0) {
            int b = c / 288, rm = c % 288, h = rm / 12, j = rm % 12;
            off = ((b * 8 + ((batch + 1) & 7)) * 576 + h * 24 + j) * 768;
        } else {
            off = ((c < M) ? (batch * 576 + c) : (batch * 576)) * 768;
        }
        offB[tid - 256] = off;
    }
    __syncthreads();

    // staging: thread covers rows r0 and 128+r0, phys chunk tid&3.
    // inverse swizzle on global source: fetch logical chunk (tid&3)^((r0>>1)&3).
    const int r0  = tid >> 2;
    const int c0s = (((tid & 3) ^ ((r0 >> 1) & 3)) << 3);
    const int sA0 = offA[r0] + c0s;
    const int sA1 = offA[128 + r0] + c0s;
    const int sB0 = offB[r0] + c0s;
    const int sB1 = offB[128 + r0] + c0s;
    const int dW  = w * 512;                 // wave-uniform LDS chunk (ushorts)

    // swizzled read offsets (ushort units within a slot)
    int aoff[8], boff[4];
#pragma unroll
    for (int i = 0; i < 8; ++i) {
        int row = wM * 128 + i * 16 + lr;
        aoff[i] = row * 32 + ((lg ^ ((row >> 1) & 3)) << 3);
    }
#pragma unroll
    for (int j = 0; j < 4; ++j) {
        int row = wN * 64 + j * 16 + lr;
        boff[j] = 8192 + row * 32 + ((lg ^ ((row >> 1) & 3)) << 3);
    }

    f32x4_t acc[8][4];
#pragma unroll
    for (int i = 0; i < 8; ++i)
#pragma unroll
        for (int j = 0; j < 4; ++j) acc[i][j] = (f32x4_t){0.f, 0.f, 0.f, 0.f};

#define SA(T) do { \
    const int sb_ = ((T) & 3) * 16384; const int k0_ = (T) * 32; \
    gl_lds16(z1b + sA0 + k0_, &smem[sb_ + dW]); \
    gl_lds16(z1b + sA1 + k0_, &smem[sb_ + 4096 + dW]); \
} while (0)
#define SB(T) do { \
    const int sb_ = ((T) & 3) * 16384; const int k0_ = (T) * 32; \
    gl_lds16(z2b + sB0 + k0_, &smem[sb_ + 8192 + dW]); \
    gl_lds16(z2b + sB1 + k0_, &smem[sb_ + 12288 + dW]); \
} while (0)

// one K32-tile, two phases of {reads ∥ stage -> bar -> lgkm0 -> 16 MFMA}.
// VM: literal vmcnt string for the tile-head wait. DO_STAGE: issue SA/SB(T+3).
#define TILE(T, VMSTR, DO_STAGE) do { \
    const unsigned short* S_ = &smem[((T) & 3) * 16384]; \
    asm volatile("s_waitcnt " VMSTR ::: "memory"); \
    __builtin_amdgcn_s_barrier(); \
    __builtin_amdgcn_sched_barrier(0); \
    bf16x8_t afl[4], afh[4], bfl[4]; \
    _Pragma("unroll") \
    for (int i = 0; i < 4; ++i) afl[i] = *(const bf16x8_t*)&S_[aoff[i]]; \
    _Pragma("unroll") \
    for (int j = 0; j < 4; ++j) bfl[j] = *(const bf16x8_t*)&S_[boff[j]]; \
    if (DO_STAGE) SA((T) + 3); \
    __builtin_amdgcn_s_barrier(); \
    asm volatile("s_waitcnt lgkmcnt(0)" ::: "memory"); \
    __builtin_amdgcn_sched_barrier(0); \
    __builtin_amdgcn_s_setprio(1); \
    _Pragma("unroll") \
    for (int i = 0; i < 4; ++i) \
        _Pragma("unroll") \
        for (int j = 0; j < 4; ++j) \
            acc[i][j] = __builtin_amdgcn_mfma_f32_16x16x32_bf16( \
                afl[i], bfl[j], acc[i][j], 0, 0, 0); \
    __builtin_amdgcn_s_setprio(0); \
    __builtin_amdgcn_s_barrier(); \
    __builtin_amdgcn_sched_barrier(0); \
    _Pragma("unroll") \
    for (int i = 0; i < 4; ++i) afh[i] = *(const bf16x8_t*)&S_[aoff[4 + i]]; \
    if (DO_STAGE) SB((T) + 3); \
    __builtin_amdgcn_s_barrier(); \
    asm volatile("s_waitcnt lgkmcnt(0)" ::: "memory"); \
    __builtin_amdgcn_sched_barrier(0); \
    __builtin_amdgcn_s_setprio(1); \
    _Pragma("unroll") \
    for (int i = 0; i < 4; ++i) \
        _Pragma("unroll") \
        for (int j = 0; j < 4; ++j) \
            acc[4 + i][j] = __builtin_amdgcn_mfma_f32_16x16x32_bf16( \
                afh[i], bfl[j], acc[4 + i][j], 0, 0, 0); \
    __builtin_amdgcn_s_setprio(0); \
} while (0)

    SA(0); SB(0); SA(1); SB(1); SA(2); SB(2);   // 12 outstanding

#pragma unroll 1
    for (int t = 0; t < 21; ++t) TILE(t, "vmcnt(8)", true);
    TILE(21, "vmcnt(4)", false);
    TILE(22, "vmcnt(2)", false);
    TILE(23, "vmcnt(0)", false);
#undef TILE
#undef SA
#undef SB

    // Epilogue: L = acc*inv_tau; exp row/col partial sums; diag.
    const int rowbase = brow * 256 + wM * 128;
    const int colbase = bcol * 256 + wN * 64;
    float colacc[4] = {0.f, 0.f, 0.f, 0.f};
#pragma unroll
    for (int i = 0; i < 8; ++i) {
#pragma unroll
        for (int reg = 0; reg < 4; ++reg) {
            int row = rowbase + i * 16 + lg * 4 + reg;
            bool rv = row < M;
            float rp = 0.f;
#pragma unroll
            for (int j = 0; j < 4; ++j) {
                int col = colbase + j * 16 + lr;
                float L = acc[i][j][reg] * inv_tau;
                float e = (rv && (col < M)) ? __expf(L) : 0.f;
                rp += e;
                colacc[j] += e;
                if (rv && row == col) diag[batch * M + row] = L;
            }
#pragma unroll
            for (int s = 1; s < 16; s <<= 1) rp += __shfl_xor(rp, s);
            if (lr == 0 && rv) atomicAdd(&rowsum[batch * M + row], rp);
        }
    }
#pragma unroll
    for (int j = 0; j < 4; ++j) {
        float cv = colacc[j];
        cv += __shfl_xor(cv, 16);
        cv += __shfl_xor(cv, 32);
        int col = colbase + j * 16 + lr;
        if (lg == 0 && col < M) atomicAdd(&colsum[batch * M + col], cv);
    }
}

// ---------------- fallback path (R1, convert-in-flight, verified) ----------
template <int MODE>
__global__ __launch_bounds__(256) void fused_gemm_lse(
    const float* __restrict__ z1, const float* __restrict__ z2,
    float* __restrict__ rowsum, float* __restrict__ colsum,
    float* __restrict__ diag) {
    constexpr int M = (MODE == 0) ? 2304 : 576;
    constexpr float inv_tau = (MODE == 0) ? (1.0f / 0.07f) : (1.0f / 0.2f);

    const int tid  = threadIdx.x;
    const int lane = tid & 63;
    const int w    = tid >> 6;
    const int wM   = w >> 1;
    const int wN   = w & 1;
    const int lr   = lane & 15;
    const int lg   = lane >> 4;
    const int brow = blockIdx.y, bcol = blockIdx.x, batch = blockIdx.z;

    __shared__ unsigned short lA[128][72];
    __shared__ unsigned short lB[128][72];
    __shared__ int offA[128];
    __shared__ int offB[128];

    if (tid < 128) {
        int r = brow * 128 + tid;
        int off;
        if (MODE == 0) {
            int b = r / 288, rem = r % 288;
            int h = rem / 12, j = rem % 12;
            off = ((b * 8 + batch) * 576 + h * 24 + 12 + j) * 768;
        } else {
            off = (r < M) ? (batch * 576 + r) * 768 : -1;
        }
        offA[tid] = off;
    } else {
        int c = bcol * 128 + (tid - 128);
        int off;
        if (MODE == 0) {
            int b = c / 288, rem = c % 288;
            int h = rem / 12, j = rem % 12;
            off = ((b * 8 + ((batch + 1) & 7)) * 576 + h * 24 + j) * 768;
        } else {
            off = (c < M) ? (batch * 576 + c) * 768 : -1;
        }
        offB[tid - 128] = off;
    }
    __syncthreads();

    f32x4_t acc[4][4];
#pragma unroll
    for (int i = 0; i < 4; ++i)
#pragma unroll
        for (int j = 0; j < 4; ++j) acc[i][j] = (f32x4_t){0.f, 0.f, 0.f, 0.f};

    for (int kt = 0; kt < 12; ++kt) {
        const int k0 = kt * 64;
#pragma unroll
        for (int rr = 0; rr < 8; ++rr) {
            int f   = tid + (rr << 8);
            int row = f >> 4;
            int c4  = f & 15;
            int oA = offA[row], oB = offB[row];
            float4 va = make_float4(0.f, 0.f, 0.f, 0.f);
            float4 vb = make_float4(0.f, 0.f, 0.f, 0.f);
            if (oA >= 0) va = *(const float4*)(z1 + oA + k0 + (c4 << 2));
            if (oB >= 0) vb = *(const float4*)(z2 + oB + k0 + (c4 << 2));
            ushort4 sa, sb;
            sa.x = f2bf(va.x); sa.y = f2bf(va.y); sa.z = f2bf(va.z); sa.w = f2bf(va.w);
            sb.x = f2bf(vb.x); sb.y = f2bf(vb.y); sb.z = f2bf(vb.z); sb.w = f2bf(vb.w);
            *(ushort4*)&lA[row][c4 << 2] = sa;
            *(ushort4*)&lB[row][c4 << 2] = sb;
        }
        __syncthreads();
#pragma unroll
        for (int kk = 0; kk < 64; kk += 32) {
            bf16x8_t av[4], bv[4];
#pragma unroll
            for (int i = 0; i < 4; ++i) {
                av[i] = *(const bf16x8_t*)&lA[wM * 64 + i * 16 + lr][kk + lg * 8];
                bv[i] = *(const bf16x8_t*)&lB[wN * 64 + i * 16 + lr][kk + lg * 8];
            }
#pragma unroll
            for (int i = 0; i < 4; ++i)
#pragma unroll
                for (int j = 0; j < 4; ++j)
                    acc[i][j] = __builtin_amdgcn_mfma_f32_16x16x32_bf16(
                        av[i], bv[j], acc[i][j], 0, 0, 0);
        }
        __syncthreads();
    }

    const int rowbase = brow * 128 + wM * 64;
    const int colbase = bcol * 128 + wN * 64;
    float colacc[4] = {0.f, 0.f, 0.f, 0.f};
#pragma unroll
    for (int i = 0; i < 4; ++i) {
#pragma unroll
        for (int reg = 0; reg < 4; ++reg) {
            int row = rowbase + i * 16 + lg * 4 + reg;
            bool rv = row < M;
            float rp = 0.f;
#pragma unroll
            for (int j = 0; j < 4; ++j) {
                int col = colbase + j * 16 + lr;
                float L = acc[i][j][reg] * inv_tau;
                float e = (rv && (col < M)) ? __expf(L) : 0.f;
                rp += e;
                colacc[j] += e;
                if (rv && row == col) diag[batch * M + row] = L;
            }
#pragma unroll
            for (int s = 1; s < 16; s <<= 1) rp += __shfl_xor(rp, s);
            if (lr == 0 && rv) atomicAdd(&rowsum[batch * M + row], rp);
        }
    }
#pragma unroll
    for (int j = 0; j < 4; ++j) {
        float c = colacc[j];
        c += __shfl_xor(c, 16);
        c += __shfl_xor(c, 32);
        int col = colbase + j * 16 + lr;
        if (lg == 0 && col < M) atomicAdd(&colsum[batch * M + col], c);
    }
}

// ws float layout:
// [0) rs_ov 18432 | [18432) cs_ov 18432 | [36864) dg_ov 18432
// [55296) rs_t 36864 | [92160) cs_t 36864 | [129024) dg_t 36864 -> 165888
// fast path: bf16 z1 copy at byte 663552, z2 after.
__global__ void finalize_kernel(const float* __restrict__ ws, float* __restrict__ out) {
    const float* rs_ov = ws;
    const float* cs_ov = ws + 18432;
    const float* dg_ov = ws + 36864;
    const float* rs_t  = ws + 55296;
    const float* cs_t  = ws + 92160;
    const float* dg_t  = ws + 129024;
    float s_ov = 0.f, s_t = 0.f;
    for (int i = threadIdx.x; i < 18432; i += 256)
        s_ov += logf(rs_ov[i]) + logf(cs_ov[i]) - 2.f * dg_ov[i];
    for (int i = threadIdx.x; i < 36864; i += 256)
        s_t += logf(rs_t[i]) + logf(cs_t[i]) - 2.f * dg_t[i];
#pragma unroll
    for (int s = 1; s < 64; s <<= 1) {
        s_ov += __shfl_xor(s_ov, s);
        s_t  += __shfl_xor(s_t, s);
    }
    __shared__ float red[2][4];
    int w = threadIdx.x >> 6;
    if ((threadIdx.x & 63) == 0) { red[0][w] = s_ov; red[1][w] = s_t; }
    __syncthreads();
    if (threadIdx.x == 0) {
        float a = red[0][0] + red[0][1] + red[0][2] + red[0][3];
        float b = red[1][0] + red[1][1] + red[1][2] + red[1][3];
        out[0] = 0.5f * a / 18432.f + 0.05f * b / 36864.f;
    }
}

extern "C" void kernel_launch(void* const* d_in, const int* in_sizes, int n_in,
                              void* d_out, int out_size, void* d_ws, size_t ws_size,
                              hipStream_t stream) {
    const float* z1 = (const float*)d_in[0];
    const float* z2 = (const float*)d_in[1];
    float* out = (float*)d_out;
    float* ws  = (float*)d_ws;

    const size_t N_ELEM = (size_t)64 * 576 * 768;
    const size_t ACC_B  = 165888 * sizeof(float);
    const size_t BF_B   = N_ELEM * 2;
    const size_t NEED   = ACC_B + 2 * BF_B;

    hipMemsetAsync(d_ws, 0, ACC_B, stream);
    dim3 blk256(256, 1, 1);

    if (ws_size >= NEED) {
        unsigned short* z1b = (unsigned short*)((char*)d_ws + ACC_B);
        unsigned short* z2b = z1b + N_ELEM;
        int n8 = (int)(N_ELEM / 8);
        f32_to_bf16<<<2048, blk256, 0, stream>>>(z1, z1b, n8);
        f32_to_bf16<<<2048, blk256, 0, stream>>>(z2, z2b, n8);
        gemm256_lse<0><<<648, 512, 0, stream>>>(
            z1b, z2b, ws, ws + 18432, ws + 36864);
        gemm256_lse<1><<<576, 512, 0, stream>>>(
            z1b, z2b, ws + 55296, ws + 92160, ws + 129024);
    } else {
        fused_gemm_lse<0><<<dim3(18, 18, 8), blk256, 0, stream>>>(
            z1, z2, ws, ws + 18432, ws + 36864);
        fused_gemm_lse<1><<<dim3(5, 5, 64), blk256, 0, stream>>>(
            z1, z2, ws + 55296, ws + 92160, ws + 129024);
    }
    finalize_kernel<<<1, 256, 0, stream>>>(ws, out);
}

// Round 6
// 289.693 us; speedup vs baseline: 1.4815x; 1.1240x over previous
//
#include <hip/hip_runtime.h>
#include <hip/hip_bf16.h>

typedef __attribute__((ext_vector_type(8))) short bf16x8_t;
typedef __attribute__((ext_vector_type(4))) float f32x4_t;
typedef __attribute__((ext_vector_type(8))) unsigned short u16x8_t;

__device__ inline unsigned short f2bf(float x) {
    union { float f; unsigned int u; } v; v.f = x;
    unsigned int r = v.u + 0x7FFFu + ((v.u >> 16) & 1u);
    return (unsigned short)(r >> 16);
}

__device__ inline void gl_lds16(const void* g, void* l) {
    __builtin_amdgcn_global_load_lds(
        (const __attribute__((address_space(1))) void*)g,
        (__attribute__((address_space(3))) void*)l, 16, 0, 0);
}

// ---------------- f32 -> bf16 convert (8 elems/thread/iter) ----------------
__global__ __launch_bounds__(256) void f32_to_bf16(
    const float* __restrict__ src, unsigned short* __restrict__ dst, int n8) {
    int stride = gridDim.x * blockDim.x;
    for (int i = blockIdx.x * blockDim.x + threadIdx.x; i < n8; i += stride) {
        const float4* p = (const float4*)(src + (size_t)i * 8);
        float4 a = p[0], b = p[1];
        u16x8_t v;
        v[0] = f2bf(a.x); v[1] = f2bf(a.y); v[2] = f2bf(a.z); v[3] = f2bf(a.w);
        v[4] = f2bf(b.x); v[5] = f2bf(b.y); v[6] = f2bf(b.z); v[7] = f2bf(b.w);
        *(u16x8_t*)(dst + (size_t)i * 8) = v;
    }
}

// ------ merged 256x256-tile GEMM+LSE: blocks 0..647 overlap, 648..1223 tile -
// BK=32, 4-slot LDS ring, ONE barrier + ONE counted vmcnt per K-tile.
// LDS slot s (32KB): A[256][32] at s*16384, B[256][32] at s*16384+8192 (ushorts).
// Swizzle: 16B-chunk phys = logical ^ ((row>>1)&3): inverse on global source,
// forward on ds_read, linear LDS dest (rule 21).  Ring: stage t+3 during t;
// steady vmcnt(8) (never drains in-loop), tail 8/4/0.
// ws float layout:
// [0) rs_ov 18432 | [18432) cs_ov 18432 | [36864) dg_ov 18432
// [55296) rs_t 36864 | [92160) cs_t 36864 | [129024) dg_t 36864 -> 165888
__global__ __launch_bounds__(512, 2) void gemm256_lse_all(
    const unsigned short* __restrict__ z1b, const unsigned short* __restrict__ z2b,
    float* __restrict__ ws) {
    const int tid  = threadIdx.x;
    const int lane = tid & 63;
    const int w    = tid >> 6;        // 0..7
    const int wM   = w >> 2;          // 0..1  (rows: wM*128)
    const int wN   = w & 3;           // 0..3  (cols: wN*64)
    const int lr   = lane & 15;
    const int lg   = lane >> 4;       // 0..3 (16B k-chunk within 32-elem row)

    // T1: XCD-aware bijective swizzle over 1224 = 8*153 blocks
    const int bid = blockIdx.x;
    const int lb  = (bid & 7) * 153 + (bid >> 3);

    int M, TM, batch, rem;
    float inv_tau;
    float *rs, *cs, *dg;
    bool ov = (lb < 648);
    if (ov) {
        M = 2304; TM = 9; inv_tau = 1.0f / 0.07f;
        rs = ws; cs = ws + 18432; dg = ws + 36864;
        batch = lb / 81; rem = lb - batch * 81;
    } else {
        M = 576; TM = 3; inv_tau = 1.0f / 0.2f;
        rs = ws + 55296; cs = ws + 92160; dg = ws + 129024;
        int tl = lb - 648;
        batch = tl / 9; rem = tl - batch * 9;
    }
    const int brow = rem / TM;
    const int bcol = rem - brow * TM;

    __shared__ unsigned short smem[65536];   // 4 slots x 16384 ushorts = 128 KiB
    __shared__ int offA[256], offB[256];

    if (tid < 256) {
        int r = brow * 256 + tid;
        int off;
        if (ov) {
            int b = r / 288, rm = r % 288, h = rm / 12, j = rm % 12;
            off = ((b * 8 + batch) * 576 + h * 24 + 12 + j) * 768;
        } else {
            off = ((r < M) ? (batch * 576 + r) : (batch * 576)) * 768;
        }
        offA[tid] = off;
    } else {
        int c = bcol * 256 + (tid - 256);
        int off;
        if (ov) {
            int b = c / 288, rm = c % 288, h = rm / 12, j = rm % 12;
            off = ((b * 8 + ((batch + 1) & 7)) * 576 + h * 24 + j) * 768;
        } else {
            off = ((c < M) ? (batch * 576 + c) : (batch * 576)) * 768;
        }
        offB[tid - 256] = off;
    }
    __syncthreads();

    // staging: thread covers rows r0 and 128+r0, phys 16B-chunk tid&3;
    // inverse swizzle on global source.
    const int r0  = tid >> 2;
    const int c0s = (((tid & 3) ^ ((r0 >> 1) & 3)) << 3);
    const int sA0 = offA[r0] + c0s;
    const int sA1 = offA[128 + r0] + c0s;
    const int sB0 = offB[r0] + c0s;
    const int sB1 = offB[128 + r0] + c0s;
    const int dW  = w * 512;                 // wave-uniform LDS chunk (ushorts)

    // swizzled read offsets (ushort units within a slot)
    int aoff[8], boff[4];
#pragma unroll
    for (int i = 0; i < 8; ++i) {
        int row = wM * 128 + i * 16 + lr;
        aoff[i] = row * 32 + ((lg ^ ((row >> 1) & 3)) << 3);
    }
#pragma unroll
    for (int j = 0; j < 4; ++j) {
        int row = wN * 64 + j * 16 + lr;
        boff[j] = 8192 + row * 32 + ((lg ^ ((row >> 1) & 3)) << 3);
    }

    f32x4_t acc[8][4];
#pragma unroll
    for (int i = 0; i < 8; ++i)
#pragma unroll
        for (int j = 0; j < 4; ++j) acc[i][j] = (f32x4_t){0.f, 0.f, 0.f, 0.f};

#define SA(T) do { \
    const int sb_ = ((T) & 3) * 16384; const int k0_ = (T) * 32; \
    gl_lds16(z1b + sA0 + k0_, &smem[sb_ + dW]); \
    gl_lds16(z1b + sA1 + k0_, &smem[sb_ + 4096 + dW]); \
} while (0)
#define SB(T) do { \
    const int sb_ = ((T) & 3) * 16384; const int k0_ = (T) * 32; \
    gl_lds16(z2b + sB0 + k0_, &smem[sb_ + 8192 + dW]); \
    gl_lds16(z2b + sB1 + k0_, &smem[sb_ + 12288 + dW]); \
} while (0)

// one K32-tile: vmcnt head-wait, one raw barrier, stage t+3, then let the
// compiler interleave 12 ds_read_b128 with 32 MFMAs (disjoint acc halves).
#define TILE(T, VMSTR, DO_STAGE) do { \
    const unsigned short* S_ = &smem[((T) & 3) * 16384]; \
    asm volatile("s_waitcnt " VMSTR ::: "memory"); \
    __builtin_amdgcn_s_barrier(); \
    if (DO_STAGE) { SA((T) + 3); SB((T) + 3); } \
    bf16x8_t af[8], bf[4]; \
    _Pragma("unroll") \
    for (int i = 0; i < 8; ++i) af[i] = *(const bf16x8_t*)&S_[aoff[i]]; \
    _Pragma("unroll") \
    for (int j = 0; j < 4; ++j) bf[j] = *(const bf16x8_t*)&S_[boff[j]]; \
    __builtin_amdgcn_s_setprio(1); \
    _Pragma("unroll") \
    for (int i = 0; i < 8; ++i) \
        _Pragma("unroll") \
        for (int j = 0; j < 4; ++j) \
            acc[i][j] = __builtin_amdgcn_mfma_f32_16x16x32_bf16( \
                af[i], bf[j], acc[i][j], 0, 0, 0); \
    __builtin_amdgcn_s_setprio(0); \
} while (0)

    SA(0); SB(0); SA(1); SB(1); SA(2); SB(2);   // 12 outstanding

#pragma unroll 4
    for (int t = 0; t < 20; ++t) TILE(t, "vmcnt(8)", true);
    TILE(20, "vmcnt(8)", true);                 // stages tile 23
    TILE(21, "vmcnt(8)", false);
    TILE(22, "vmcnt(4)", false);
    TILE(23, "vmcnt(0)", false);
#undef TILE
#undef SA
#undef SB

    // Epilogue: L = acc*inv_tau; exp row/col partial sums; diag.
    const int rowbase = brow * 256 + wM * 128;
    const int colbase = bcol * 256 + wN * 64;
    float colacc[4] = {0.f, 0.f, 0.f, 0.f};
#pragma unroll
    for (int i = 0; i < 8; ++i) {
#pragma unroll
        for (int reg = 0; reg < 4; ++reg) {
            int row = rowbase + i * 16 + lg * 4 + reg;
            bool rv = row < M;
            float rp = 0.f;
#pragma unroll
            for (int j = 0; j < 4; ++j) {
                int col = colbase + j * 16 + lr;
                float L = acc[i][j][reg] * inv_tau;
                float e = (rv && (col < M)) ? __expf(L) : 0.f;
                rp += e;
                colacc[j] += e;
                if (rv && row == col) dg[batch * M + row] = L;
            }
#pragma unroll
            for (int s = 1; s < 16; s <<= 1) rp += __shfl_xor(rp, s);
            if (lr == 0 && rv) atomicAdd(&rs[batch * M + row], rp);
        }
    }
#pragma unroll
    for (int j = 0; j < 4; ++j) {
        float cv = colacc[j];
        cv += __shfl_xor(cv, 16);
        cv += __shfl_xor(cv, 32);
        int col = colbase + j * 16 + lr;
        if (lg == 0 && col < M) atomicAdd(&cs[batch * M + col], cv);
    }
}

// ---------------- fallback path (R1, convert-in-flight, verified) ----------
template <int MODE>
__global__ __launch_bounds__(256) void fused_gemm_lse(
    const float* __restrict__ z1, const float* __restrict__ z2,
    float* __restrict__ rowsum, float* __restrict__ colsum,
    float* __restrict__ diag) {
    constexpr int M = (MODE == 0) ? 2304 : 576;
    constexpr float inv_tau = (MODE == 0) ? (1.0f / 0.07f) : (1.0f / 0.2f);

    const int tid  = threadIdx.x;
    const int lane = tid & 63;
    const int w    = tid >> 6;
    const int wM   = w >> 1;
    const int wN   = w & 1;
    const int lr   = lane & 15;
    const int lg   = lane >> 4;
    const int brow = blockIdx.y, bcol = blockIdx.x, batch = blockIdx.z;

    __shared__ unsigned short lA[128][72];
    __shared__ unsigned short lB[128][72];
    __shared__ int offA[128];
    __shared__ int offB[128];

    if (tid < 128) {
        int r = brow * 128 + tid;
        int off;
        if (MODE == 0) {
            int b = r / 288, rem = r % 288;
            int h = rem / 12, j = rem % 12;
            off = ((b * 8 + batch) * 576 + h * 24 + 12 + j) * 768;
        } else {
            off = (r < M) ? (batch * 576 + r) * 768 : -1;
        }
        offA[tid] = off;
    } else {
        int c = bcol * 128 + (tid - 128);
        int off;
        if (MODE == 0) {
            int b = c / 288, rem = c % 288;
            int h = rem / 12, j = rem % 12;
            off = ((b * 8 + ((batch + 1) & 7)) * 576 + h * 24 + j) * 768;
        } else {
            off = (c < M) ? (batch * 576 + c) * 768 : -1;
        }
        offB[tid - 128] = off;
    }
    __syncthreads();

    f32x4_t acc[4][4];
#pragma unroll
    for (int i = 0; i < 4; ++i)
#pragma unroll
        for (int j = 0; j < 4; ++j) acc[i][j] = (f32x4_t){0.f, 0.f, 0.f, 0.f};

    for (int kt = 0; kt < 12; ++kt) {
        const int k0 = kt * 64;
#pragma unroll
        for (int rr = 0; rr < 8; ++rr) {
            int f   = tid + (rr << 8);
            int row = f >> 4;
            int c4  = f & 15;
            int oA = offA[row], oB = offB[row];
            float4 va = make_float4(0.f, 0.f, 0.f, 0.f);
            float4 vb = make_float4(0.f, 0.f, 0.f, 0.f);
            if (oA >= 0) va = *(const float4*)(z1 + oA + k0 + (c4 << 2));
            if (oB >= 0) vb = *(const float4*)(z2 + oB + k0 + (c4 << 2));
            ushort4 sa, sb;
            sa.x = f2bf(va.x); sa.y = f2bf(va.y); sa.z = f2bf(va.z); sa.w = f2bf(va.w);
            sb.x = f2bf(vb.x); sb.y = f2bf(vb.y); sb.z = f2bf(vb.z); sb.w = f2bf(vb.w);
            *(ushort4*)&lA[row][c4 << 2] = sa;
            *(ushort4*)&lB[row][c4 << 2] = sb;
        }
        __syncthreads();
#pragma unroll
        for (int kk = 0; kk < 64; kk += 32) {
            bf16x8_t av[4], bv[4];
#pragma unroll
            for (int i = 0; i < 4; ++i) {
                av[i] = *(const bf16x8_t*)&lA[wM * 64 + i * 16 + lr][kk + lg * 8];
                bv[i] = *(const bf16x8_t*)&lB[wN * 64 + i * 16 + lr][kk + lg * 8];
            }
#pragma unroll
            for (int i = 0; i < 4; ++i)
#pragma unroll
                for (int j = 0; j < 4; ++j)
                    acc[i][j] = __builtin_amdgcn_mfma_f32_16x16x32_bf16(
                        av[i], bv[j], acc[i][j], 0, 0, 0);
        }
        __syncthreads();
    }

    const int rowbase = brow * 128 + wM * 64;
    const int colbase = bcol * 128 + wN * 64;
    float colacc[4] = {0.f, 0.f, 0.f, 0.f};
#pragma unroll
    for (int i = 0; i < 4; ++i) {
#pragma unroll
        for (int reg = 0; reg < 4; ++reg) {
            int row = rowbase + i * 16 + lg * 4 + reg;
            bool rv = row < M;
            float rp = 0.f;
#pragma unroll
            for (int j = 0; j < 4; ++j) {
                int col = colbase + j * 16 + lr;
                float L = acc[i][j][reg] * inv_tau;
                float e = (rv && (col < M)) ? __expf(L) : 0.f;
                rp += e;
                colacc[j] += e;
                if (rv && row == col) diag[batch * M + row] = L;
            }
#pragma unroll
            for (int s = 1; s < 16; s <<= 1) rp += __shfl_xor(rp, s);
            if (lr == 0 && rv) atomicAdd(&rowsum[batch * M + row], rp);
        }
    }
#pragma unroll
    for (int j = 0; j < 4; ++j) {
        float c = colacc[j];
        c += __shfl_xor(c, 16);
        c += __shfl_xor(c, 32);
        int col = colbase + j * 16 + lr;
        if (lg == 0 && col < M) atomicAdd(&colsum[batch * M + col], c);
    }
}

__global__ void finalize_kernel(const float* __restrict__ ws, float* __restrict__ out) {
    const float* rs_ov = ws;
    const float* cs_ov = ws + 18432;
    const float* dg_ov = ws + 36864;
    const float* rs_t  = ws + 55296;
    const float* cs_t  = ws + 92160;
    const float* dg_t  = ws + 129024;
    float s_ov = 0.f, s_t = 0.f;
    for (int i = threadIdx.x; i < 18432; i += 256)
        s_ov += logf(rs_ov[i]) + logf(cs_ov[i]) - 2.f * dg_ov[i];
    for (int i = threadIdx.x; i < 36864; i += 256)
        s_t += logf(rs_t[i]) + logf(cs_t[i]) - 2.f * dg_t[i];
#pragma unroll
    for (int s = 1; s < 64; s <<= 1) {
        s_ov += __shfl_xor(s_ov, s);
        s_t  += __shfl_xor(s_t, s);
    }
    __shared__ float red[2][4];
    int w = threadIdx.x >> 6;
    if ((threadIdx.x & 63) == 0) { red[0][w] = s_ov; red[1][w] = s_t; }
    __syncthreads();
    if (threadIdx.x == 0) {
        float a = red[0][0] + red[0][1] + red[0][2] + red[0][3];
        float b = red[1][0] + red[1][1] + red[1][2] + red[1][3];
        out[0] = 0.5f * a / 18432.f + 0.05f * b / 36864.f;
    }
}

extern "C" void kernel_launch(void* const* d_in, const int* in_sizes, int n_in,
                              void* d_out, int out_size, void* d_ws, size_t ws_size,
                              hipStream_t stream) {
    const float* z1 = (const float*)d_in[0];
    const float* z2 = (const float*)d_in[1];
    float* out = (float*)d_out;
    float* ws  = (float*)d_ws;

    const size_t N_ELEM = (size_t)64 * 576 * 768;
    const size_t ACC_B  = 165888 * sizeof(float);
    const size_t BF_B   = N_ELEM * 2;
    const size_t NEED   = ACC_B + 2 * BF_B;

    hipMemsetAsync(d_ws, 0, ACC_B, stream);
    dim3 blk256(256, 1, 1);

    if (ws_size >= NEED) {
        unsigned short* z1b = (unsigned short*)((char*)d_ws + ACC_B);
        unsigned short* z2b = z1b + N_ELEM;
        int n8 = (int)(N_ELEM / 8);
        f32_to_bf16<<<2048, blk256, 0, stream>>>(z1, z1b, n8);
        f32_to_bf16<<<2048, blk256, 0, stream>>>(z2, z2b, n8);
        gemm256_lse_all<<<1224, 512, 0, stream>>>(z1b, z2b, ws);
    } else {
        fused_gemm_lse<0><<<dim3(18, 18, 8), blk256, 0, stream>>>(
            z1, z2, ws, ws + 18432, ws + 36864);
        fused_gemm_lse<1><<<dim3(5, 5, 64), blk256, 0, stream>>>(
            z1, z2, ws + 55296, ws + 92160, ws + 129024);
    }
    finalize_kernel<<<1, 256, 0, stream>>>(ws, out);
}